// Round 4
// baseline (239.845 us; speedup 1.0000x reference)
//
#include <hip/hip_runtime.h>
#include <hip/hip_fp8.h>

// Problem constants (from reference)
#define VOCAB 50000
#define DIM   50
#define B_TOT 131072
#define CTX   10
#define NEG   10
#define EPS_F 1e-10f
#define PAIRS (B_TOT / 2)

constexpr int TPB    = 256;   // 4 waves
constexpr int BLOCKS = 4096;  // 16384 waves x 4 pair-iterations (exact)
constexpr int NWAVES = BLOCKS * (TPB / 64);
constexpr int ITERS  = PAIRS / NWAVES;           // = 4
static_assert(PAIRS % NWAVES == 0, "exact division required");

// fp8 table layout in d_ws: each row padded to ONE aligned 64B line.
constexpr size_t ROW8_B  = 64;
constexpr size_t TAB8_B  = (size_t)VOCAB * ROW8_B;   // 3.2 MB per table
constexpr size_t WS_NEED = 2 * TAB8_B + 64;

// R16 vs R15 (113.4us): R15's table phase-split REGRESSED (+2.4 vs R13's
// 111.0) -> L2-thrash hypothesis falsified; revert to the R13 loss core
// (double-buffered 42-row tiles, counted vmcnt(3), preloaded indices).
// New in R16: cut fixed overhead, not the (already-pipelined) loss loop:
//  - finalize kernel FUSED into the loss kernel via last-block pattern:
//    per-block atomicAdd into one device-scope f32 accumulator (coherent at
//    LLC across XCDs), __threadfence(), ticket atomicAdd; the block drawing
//    ticket==BLOCKS-1 reads acc (atomic read) and writes out[0]. One fewer
//    dispatch + gap. cbow_convert (same-stream, earlier) zeroes acc/ticket
//    each run so workspace poison is harmless.
//  - convert kernel: 2 fp8-pairs per thread (one 4B store vs two 2B), half
//    the threads/blocks.
// Retained: fp8 64B-line rows (R7), global_load_lds row-DMA (R8), stride-21
// LDS + team-split ctx + all-DPP reductions (R10/R11), float2 packed math +
// -log1pexp loss (R12), preloaded indices + counted-vmcnt dbuf (R13).
constexpr int BUF_W = 42 * 16;       // 672 words = 2688 B per wave buffer

typedef float vf2 __attribute__((ext_vector_type(2)));

static __device__ __forceinline__ void fp8x8_to_vf2x4(unsigned long long w,
                                                      vf2* f) {
#if __has_builtin(__builtin_amdgcn_cvt_pk_f32_fp8)
    const int lo = (int)(unsigned int)w;
    const int hi = (int)(unsigned int)(w >> 32);
    f[0] = __builtin_amdgcn_cvt_pk_f32_fp8(lo, false);
    f[1] = __builtin_amdgcn_cvt_pk_f32_fp8(lo, true);
    f[2] = __builtin_amdgcn_cvt_pk_f32_fp8(hi, false);
    f[3] = __builtin_amdgcn_cvt_pk_f32_fp8(hi, true);
#else
    #pragma unroll
    for (int i = 0; i < 4; ++i) {
        __hip_fp8_e4m3 a, b;
        a.__x = (unsigned char)(w >> (16 * i));
        b.__x = (unsigned char)(w >> (16 * i + 8));
        f[i][0] = (float)a;
        f[i][1] = (float)b;
    }
#endif
}

static __device__ __forceinline__ int fp8pk(float x, float y) {
#if __has_builtin(__builtin_amdgcn_cvt_pk_fp8_f32)
    return __builtin_amdgcn_cvt_pk_fp8_f32(x, y, 0, false) & 0xffff;
#else
    __hip_fp8_e4m3 a(x), b(y);
    return (int)(a.__x | (b.__x << 8));
#endif
}

// x + partner(x) via DPP (VALU pipe). CTRL: 0xB1 quad xor1, 0x4E quad xor2,
// 0x141 row_half_mirror (quad-pair partner once quads are uniform),
// 0x128 row_ror:8 (pairs 8-lane groups within 16-lane rows).
template <int CTRL>
static __device__ __forceinline__ float dpp_add(float x) {
    const int y = __builtin_amdgcn_mov_dpp(__float_as_int(x), CTRL, 0xF, 0xF, true);
    return x + __int_as_float(y);
}

// ---- prologue: f32 tables -> fp8 rows padded to 64B lines ----
// Also zeroes the loss accumulator + ticket (same-stream ordering makes
// this visible to the loss kernel; re-runs re-zero after harness poison).
__global__ __launch_bounds__(256) void cbow_convert(
    const float* __restrict__ inW, const float* __restrict__ outW,
    unsigned int* __restrict__ ws8w,    // 2*VOCAB*16 dwords (64B rows)
    float* __restrict__ acc, unsigned int* __restrict__ ticket)
{
    const int t = blockIdx.x * 256 + threadIdx.x;
    if (t == 0) { *acc = 0.f; *ticket = 0u; }
    const int per_tab = VOCAB * 16;
    if (t >= 2 * per_tab) return;
    const int tab = t / per_tab;
    const int rem = t - tab * per_tab;
    const int r   = rem >> 4;
    const int j2  = rem & 15;            // dword within the 64B row

    unsigned int u = 0;
    if (j2 < 13) {                       // dwords 0..12 carry 50 values
        const float2* src2 = (const float2*)(tab ? outW : inW);
        const float2 v0 = src2[r * 25 + 2 * j2];
        int pk = fp8pk(v0.x, v0.y);
        if (j2 < 12) {
            const float2 v1 = src2[r * 25 + 2 * j2 + 1];
            pk |= fp8pk(v1.x, v1.y) << 16;
        }
        u = (unsigned int)pk;
    }
    ws8w[(size_t)tab * per_tab + (size_t)r * 16 + j2] = u;
}

// ---- main (R13 core + fused finalize) ----
__global__ __launch_bounds__(TPB, 7) void cbow_loss_fp8(
    const int* __restrict__ ctx_idx,    // [B, CTX]
    const int* __restrict__ pos_idx,    // [B]
    const int* __restrict__ neg_idx,    // [B, NEG]
    const unsigned short* __restrict__ ws8,  // fp8 tables (in | out)
    float* __restrict__ acc,            // device-scope accumulator
    unsigned int* __restrict__ ticket,  // arrival counter
    float* __restrict__ out)            // final scalar
{
    // double-buffered: 2 x 42 rows x 64B per wave
    __shared__ unsigned int lds[(TPB / 64) * 2 * BUF_W];   // 21504 B

    const int lane = threadIdx.x & 63;
    const int sub  = lane >> 5;          // half-wave -> sample
    const int l    = lane & 31;
    const int quad = lane >> 2;          // 0..15: row within a 16-row DMA
    const int qb   = (lane & 3) * 16;    // byte offset within the 64B row
    const int g    = (l >> 3) & 3;       // 8-lane group within half-wave
    const int j    = l & 7;              // lane within group

    const int wave  = threadIdx.x >> 6;
    unsigned int* wbase = lds + wave * (2 * BUF_W);
    const int gwave = blockIdx.x * (TPB / 64) + wave;

    const char* in8  = (const char*)ws8;
    const char* out8 = (const char*)(ws8 + (size_t)VOCAB * 32);

    // lane -> index slot: l<10: ctx[l]; l==10: pos; 11..20: neg[l-11]
    auto idx_addr = [&](int b) -> const int* {
        if (l < CTX)           return ctx_idx + b * CTX + l;
        if (l == CTX)          return pos_idx + b;
        if (l < CTX + 1 + NEG) return neg_idx + b * NEG + (l - CTX - 1);
        return pos_idx + b;    // lanes 21..31: harmless dummy
    };

    // ---- preload ALL iteration indices; drain vmcnt so the pipeline's
    //      counted waits see only our row-DMAs ----
    int my_idx[ITERS];
    #pragma unroll
    for (int i = 0; i < ITERS; ++i)
        my_idx[i] = *idx_addr(2 * (gwave + i * NWAVES) + sub);
    asm volatile("s_waitcnt vmcnt(0)" ::: "memory");

    // 42 row-DMAs (2 samples x 21, stride 21 rows) into buffer `dst`
    auto issue = [&](unsigned int* dst, int midx) {
        #pragma unroll
        for (int t = 0; t < 3; ++t) {
            const int row  = t * 16 + quad;            // 0..47
            const int crow = (row > 41) ? 41 : row;    // clamp dead rows
            const int sample = (crow >= 21) ? 1 : 0;
            const int slot   = crow - 21 * sample;     // 0..20
            // shfl with ALL lanes active (R10 bug: masked source lanes)
            const int idx = __shfl(midx, sample * 32 + slot);
            if (t < 2 || lane < 40) {                  // rows 42..47: no DMA
                const char* tb = (slot < CTX) ? in8 : out8;
                const char* ga = tb + ((size_t)(unsigned)idx << 6) + qb;
                __builtin_amdgcn_global_load_lds(
                    (const __attribute__((address_space(1))) unsigned int*)ga,
                    (__attribute__((address_space(3))) unsigned int*)(dst + t * 256),
                    16, 0, 0);
            }
        }
    };

    float loss_lane = 0.f;

    // ---- prologue: fill buffer 0 for iter 0 ----
    issue(wbase, my_idx[0]);

    #pragma unroll
    for (int i = 0; i < ITERS; ++i) {
        // issue next iter's DMAs into the other buffer, then wait ONLY for
        // the current buffer's 3 (older, in-order) DMAs.
        if (i + 1 < ITERS) {
            issue(wbase + ((i + 1) & 1) * BUF_W, my_idx[i + 1]);
            asm volatile("s_waitcnt vmcnt(3)" ::: "memory");
        } else {
            asm volatile("s_waitcnt vmcnt(0)" ::: "memory");
        }

        const unsigned int* buf = wbase + (i & 1) * BUF_W;
        const char* smp = (const char*)buf + sub * (21 * 64);

        // ---- ctx partial: team (g&1) sums rows team*5 .. team*5+4 ----
        vf2 cv[4] = {vf2{0.f, 0.f}, vf2{0.f, 0.f}, vf2{0.f, 0.f}, vf2{0.f, 0.f}};
        #pragma unroll
        for (int s = 0; s < 5; ++s) {
            const int r = (g & 1) * 5 + s;
            const unsigned long long w =
                *(const unsigned long long*)(smp + r * 64 + j * 8);
            vf2 f[4];
            fp8x8_to_vf2x4(w, f);
            #pragma unroll
            for (int d = 0; d < 4; ++d) cv[d] += f[d];   // v_pk_add_f32
        }
        // cross-team combine: g <-> g^1 via DPP row_ror:8 (VALU)
        #pragma unroll
        for (int d = 0; d < 4; ++d) {
            cv[d][0] = dpp_add<0x128>(cv[d][0]);
            cv[d][1] = dpp_add<0x128>(cv[d][1]);
        }
        // (1/CTX) folded into the score below

        // ---- scores: 4 rows per pass (group g -> slot 10+4p+g) ----
        #pragma unroll
        for (int p = 0; p < 3; ++p) {
            int r = 10 + 4 * p + g;                    // 10..21
            r = (r > 20) ? 20 : r;                     // g3,p2: dup (masked)
            const unsigned long long w =
                *(const unsigned long long*)(smp + r * 64 + j * 8);
            vf2 f[4];
            fp8x8_to_vf2x4(w, f);
            vf2 acc2 = {0.f, 0.f};
            #pragma unroll
            for (int d = 0; d < 4; ++d) acc2 += cv[d] * f[d];  // v_pk_fma_f32
            float prod = acc2[0] + acc2[1];
            // 8-lane reduce, all DPP: xor1, xor2, then quad-pair partner
            prod = dpp_add<0xB1>(prod);
            prod = dpp_add<0x4E>(prod);
            prod = dpp_add<0x141>(prod);

            const bool valid = (j == 0) && !(p == 2 && g == 3);
            const float sc   = prod * (1.f / CTX);
            const float z    = (p == 0 && g == 0) ? sc : -sc;
            // log(sigmoid(z)+eps) ~= -log(1+exp(-z))  (|err| <= 9e-4)
            const float c    = -__logf(1.f + __expf(-z));
            loss_lane += valid ? c : 0.f;
        }
    }

    // ---- final cross-lane reduce ----
    loss_lane += __shfl_xor(loss_lane, 1);
    loss_lane += __shfl_xor(loss_lane, 2);
    loss_lane += __shfl_xor(loss_lane, 4);
    loss_lane += __shfl_xor(loss_lane, 8);
    loss_lane += __shfl_xor(loss_lane, 16);
    loss_lane += __shfl_xor(loss_lane, 32);

    __shared__ float s_part[TPB / 64];
    if (lane == 0) s_part[wave] = loss_lane;
    __syncthreads();
    if (threadIdx.x == 0) {
        float s = 0.f;
        #pragma unroll
        for (int w = 0; w < TPB / 64; ++w) s += s_part[w];
        // fused finalize: device-scope accumulate, last block writes out.
        atomicAdd(acc, s);
        __threadfence();
        const unsigned int t = atomicAdd(ticket, 1u);
        if (t == (unsigned int)(BLOCKS - 1)) {
            const float tot = atomicAdd(acc, 0.f);   // coherent read
            out[0] = -tot * (1.f / (float)B_TOT);
        }
    }
}

// ---- fallback (f32 tables) if ws_size is too small ----
__global__ __launch_bounds__(TPB) void cbow_loss_f32(
    const int*   __restrict__ ctx_idx, const int* __restrict__ pos_idx,
    const int*   __restrict__ neg_idx, const float* __restrict__ inW,
    const float* __restrict__ outW,    float* __restrict__ partials)
{
    const int lane = threadIdx.x & 63;
    const int sub  = lane >> 5;
    const int l    = lane & 31;
    const int p    = (l < 25) ? l : 24;
    const bool act = (l < 25);
    const int wave   = threadIdx.x >> 6;
    const int gwave  = blockIdx.x * (TPB / 64) + wave;
    const float2* inW2  = (const float2*)inW;
    const float2* outW2 = (const float2*)outW;

    float loss_lane = 0.f;
    for (int pair = gwave; pair < PAIRS; pair += NWAVES) {
        const int b = 2 * pair + sub;
        float cvx = 0.f, cvy = 0.f;
        #pragma unroll
        for (int jj = 0; jj < CTX; ++jj) {
            const float2 v = inW2[ctx_idx[b * CTX + jj] * 25 + p];
            cvx += v.x; cvy += v.y;
        }
        cvx *= (1.f / CTX); cvy *= (1.f / CTX);
        float packed = 0.f;
        #pragma unroll
        for (int r = 0; r <= NEG; ++r) {
            const int idx = (r == 0) ? pos_idx[b] : neg_idx[b * NEG + r - 1];
            const float2 v = outW2[idx * 25 + p];
            float prod = act ? (cvx * v.x + cvy * v.y) : 0.f;
            prod += __shfl_xor(prod, 1);
            prod += __shfl_xor(prod, 2);
            prod += __shfl_xor(prod, 4);
            prod += __shfl_xor(prod, 8);
            prod += __shfl_xor(prod, 16);
            packed = (l == r) ? prod : packed;
        }
        const float z   = (l == 0) ? packed : -packed;
        const float sig = 1.f / (1.f + __expf(-z));
        loss_lane += (l < NEG + 1) ? __logf(sig + EPS_F) : 0.f;
    }
    loss_lane += __shfl_xor(loss_lane, 1);
    loss_lane += __shfl_xor(loss_lane, 2);
    loss_lane += __shfl_xor(loss_lane, 4);
    loss_lane += __shfl_xor(loss_lane, 8);
    loss_lane += __shfl_xor(loss_lane, 16);
    loss_lane += __shfl_xor(loss_lane, 32);
    __shared__ float s_part[TPB / 64];
    if (lane == 0) s_part[wave] = loss_lane;
    __syncthreads();
    if (threadIdx.x == 0) {
        float s = 0.f;
        #pragma unroll
        for (int w = 0; w < TPB / 64; ++w) s += s_part[w];
        partials[blockIdx.x] = s;
    }
}

__global__ __launch_bounds__(256) void cbow_finalize(
    const float* __restrict__ partials, float* __restrict__ out)
{
    float s = 0.f;
    for (int i = threadIdx.x; i < BLOCKS; i += 256) s += partials[i];
    #pragma unroll
    for (int k = 32; k >= 1; k >>= 1) s += __shfl_xor(s, k);
    __shared__ float sm[4];
    const int w = threadIdx.x >> 6;
    if ((threadIdx.x & 63) == 0) sm[w] = s;
    __syncthreads();
    if (threadIdx.x == 0)
        out[0] = -(sm[0] + sm[1] + sm[2] + sm[3]) * (1.f / (float)B_TOT);
}

extern "C" void kernel_launch(void* const* d_in, const int* in_sizes, int n_in,
                              void* d_out, int out_size, void* d_ws, size_t ws_size,
                              hipStream_t stream) {
    const int*   ctx_idx = (const int*)  d_in[0];
    const int*   pos_idx = (const int*)  d_in[1];
    const int*   neg_idx = (const int*)  d_in[2];
    const float* inW     = (const float*)d_in[3];
    const float* outW    = (const float*)d_in[4];
    float*       out     = (float*)d_out;

    if (ws_size >= WS_NEED) {
        unsigned int* ws8w = (unsigned int*)d_ws;
        float*        acc    = (float*)((char*)d_ws + 2 * TAB8_B);
        unsigned int* ticket = (unsigned int*)((char*)d_ws + 2 * TAB8_B + 4);
        const int conv_threads = 2 * VOCAB * 16;
        cbow_convert<<<(conv_threads + 255) / 256, 256, 0, stream>>>(
            inW, outW, ws8w, acc, ticket);
        cbow_loss_fp8<<<BLOCKS, TPB, 0, stream>>>(
            ctx_idx, pos_idx, neg_idx, (const unsigned short*)d_ws,
            acc, ticket, out);
    } else {
        float* partials = (float*)d_ws;
        cbow_loss_f32<<<BLOCKS, TPB, 0, stream>>>(ctx_idx, pos_idx, neg_idx, inW, outW, partials);
        cbow_finalize<<<1, 256, 0, stream>>>(partials, out);
    }
}

// Round 5
// 111.118 us; speedup vs baseline: 2.1585x; 2.1585x over previous
//
#include <hip/hip_runtime.h>
#include <hip/hip_fp8.h>

// Problem constants (from reference)
#define VOCAB 50000
#define DIM   50
#define B_TOT 131072
#define CTX   10
#define NEG   10
#define EPS_F 1e-10f
#define PAIRS (B_TOT / 2)

constexpr int TPB    = 256;   // 4 waves
constexpr int BLOCKS = 4096;  // 16384 waves x 4 pair-iterations (exact)
constexpr int NWAVES = BLOCKS * (TPB / 64);
constexpr int ITERS  = PAIRS / NWAVES;           // = 4
static_assert(PAIRS % NWAVES == 0, "exact division required");

// fp8 table layout in d_ws: each row padded to ONE aligned 64B line.
constexpr size_t ROW8_B  = 64;
constexpr size_t TAB8_B  = (size_t)VOCAB * ROW8_B;   // 3.2 MB per table
constexpr size_t WS_NEED = 2 * TAB8_B + BLOCKS * 4;

// R17 vs R16 (239.8us!): R16's fused finalize REGRESSED 2.1x. Counter
// evidence: loss dispatch 165us even on warm replays (hbm_bytes ~0.26MB)
// -> not fetch; the added tail was 4096 blocks x 2 same-LINE device-scope
// atomic RMWs (acc/ticket 4B apart) + __threadfence() each. Same-address
// atomics serialize (data-dependent RMW, no pipelining) -> ~8192 x ~15-30ns
// = the whole regression. LESSON: one-atomic-per-block is fine at small
// grids; at 4096 blocks on one cache line it dominates. The 3us finalize
// dispatch was never worth fusing.
// R17 = exact R13 loss core (verified 111.0us: double-buffered 42-row
// tiles, counted vmcnt(3), preloaded indices, plain partials store +
// separate finalize) + R16's convert tweak (dword stores, half threads;
// byte layout verified identical by R16 absmax 0.0).
// Retained: fp8 64B-line rows (R7), global_load_lds row-DMA (R8), stride-21
// LDS + team-split ctx + all-DPP reductions (R10/R11), float2 packed math +
// -log1pexp loss (R12), preloaded indices + counted-vmcnt dbuf (R13).
constexpr int BUF_W = 42 * 16;       // 672 words = 2688 B per wave buffer

typedef float vf2 __attribute__((ext_vector_type(2)));

static __device__ __forceinline__ void fp8x8_to_vf2x4(unsigned long long w,
                                                      vf2* f) {
#if __has_builtin(__builtin_amdgcn_cvt_pk_f32_fp8)
    const int lo = (int)(unsigned int)w;
    const int hi = (int)(unsigned int)(w >> 32);
    f[0] = __builtin_amdgcn_cvt_pk_f32_fp8(lo, false);
    f[1] = __builtin_amdgcn_cvt_pk_f32_fp8(lo, true);
    f[2] = __builtin_amdgcn_cvt_pk_f32_fp8(hi, false);
    f[3] = __builtin_amdgcn_cvt_pk_f32_fp8(hi, true);
#else
    #pragma unroll
    for (int i = 0; i < 4; ++i) {
        __hip_fp8_e4m3 a, b;
        a.__x = (unsigned char)(w >> (16 * i));
        b.__x = (unsigned char)(w >> (16 * i + 8));
        f[i][0] = (float)a;
        f[i][1] = (float)b;
    }
#endif
}

static __device__ __forceinline__ int fp8pk(float x, float y) {
#if __has_builtin(__builtin_amdgcn_cvt_pk_fp8_f32)
    return __builtin_amdgcn_cvt_pk_fp8_f32(x, y, 0, false) & 0xffff;
#else
    __hip_fp8_e4m3 a(x), b(y);
    return (int)(a.__x | (b.__x << 8));
#endif
}

// x + partner(x) via DPP (VALU pipe). CTRL: 0xB1 quad xor1, 0x4E quad xor2,
// 0x141 row_half_mirror (quad-pair partner once quads are uniform),
// 0x128 row_ror:8 (pairs 8-lane groups within 16-lane rows).
template <int CTRL>
static __device__ __forceinline__ float dpp_add(float x) {
    const int y = __builtin_amdgcn_mov_dpp(__float_as_int(x), CTRL, 0xF, 0xF, true);
    return x + __int_as_float(y);
}

// ---- prologue: f32 tables -> fp8 rows padded to 64B lines ----
// Dword stores: 2 fp8-pairs per thread, half the threads of the ushort
// version; byte layout identical (verified on HW, R16 absmax 0.0).
__global__ __launch_bounds__(256) void cbow_convert(
    const float* __restrict__ inW, const float* __restrict__ outW,
    unsigned int* __restrict__ ws8w)    // 2*VOCAB*16 dwords (64B rows)
{
    const int t = blockIdx.x * 256 + threadIdx.x;
    const int per_tab = VOCAB * 16;
    if (t >= 2 * per_tab) return;
    const int tab = t / per_tab;
    const int rem = t - tab * per_tab;
    const int r   = rem >> 4;
    const int j2  = rem & 15;            // dword within the 64B row

    unsigned int u = 0;
    if (j2 < 13) {                       // dwords 0..12 carry 50 values
        const float2* src2 = (const float2*)(tab ? outW : inW);
        const float2 v0 = src2[r * 25 + 2 * j2];
        int pk = fp8pk(v0.x, v0.y);
        if (j2 < 12) {
            const float2 v1 = src2[r * 25 + 2 * j2 + 1];
            pk |= fp8pk(v1.x, v1.y) << 16;
        }
        u = (unsigned int)pk;
    }
    ws8w[(size_t)tab * per_tab + (size_t)r * 16 + j2] = u;
}

// ---- main (exact R13 core) ----
__global__ __launch_bounds__(TPB, 7) void cbow_loss_fp8(
    const int* __restrict__ ctx_idx,    // [B, CTX]
    const int* __restrict__ pos_idx,    // [B]
    const int* __restrict__ neg_idx,    // [B, NEG]
    const unsigned short* __restrict__ ws8,  // fp8 tables (in | out)
    float* __restrict__ partials)       // [BLOCKS]
{
    // double-buffered: 2 x 42 rows x 64B per wave
    __shared__ unsigned int lds[(TPB / 64) * 2 * BUF_W];   // 21504 B

    const int lane = threadIdx.x & 63;
    const int sub  = lane >> 5;          // half-wave -> sample
    const int l    = lane & 31;
    const int quad = lane >> 2;          // 0..15: row within a 16-row DMA
    const int qb   = (lane & 3) * 16;    // byte offset within the 64B row
    const int g    = (l >> 3) & 3;       // 8-lane group within half-wave
    const int j    = l & 7;              // lane within group

    const int wave  = threadIdx.x >> 6;
    unsigned int* wbase = lds + wave * (2 * BUF_W);
    const int gwave = blockIdx.x * (TPB / 64) + wave;

    const char* in8  = (const char*)ws8;
    const char* out8 = (const char*)(ws8 + (size_t)VOCAB * 32);

    // lane -> index slot: l<10: ctx[l]; l==10: pos; 11..20: neg[l-11]
    auto idx_addr = [&](int b) -> const int* {
        if (l < CTX)           return ctx_idx + b * CTX + l;
        if (l == CTX)          return pos_idx + b;
        if (l < CTX + 1 + NEG) return neg_idx + b * NEG + (l - CTX - 1);
        return pos_idx + b;    // lanes 21..31: harmless dummy
    };

    // ---- preload ALL iteration indices; drain vmcnt so the pipeline's
    //      counted waits see only our row-DMAs ----
    int my_idx[ITERS];
    #pragma unroll
    for (int i = 0; i < ITERS; ++i)
        my_idx[i] = *idx_addr(2 * (gwave + i * NWAVES) + sub);
    asm volatile("s_waitcnt vmcnt(0)" ::: "memory");

    // 42 row-DMAs (2 samples x 21, stride 21 rows) into buffer `dst`
    auto issue = [&](unsigned int* dst, int midx) {
        #pragma unroll
        for (int t = 0; t < 3; ++t) {
            const int row  = t * 16 + quad;            // 0..47
            const int crow = (row > 41) ? 41 : row;    // clamp dead rows
            const int sample = (crow >= 21) ? 1 : 0;
            const int slot   = crow - 21 * sample;     // 0..20
            // shfl with ALL lanes active (R10 bug: masked source lanes)
            const int idx = __shfl(midx, sample * 32 + slot);
            if (t < 2 || lane < 40) {                  // rows 42..47: no DMA
                const char* tb = (slot < CTX) ? in8 : out8;
                const char* ga = tb + ((size_t)(unsigned)idx << 6) + qb;
                __builtin_amdgcn_global_load_lds(
                    (const __attribute__((address_space(1))) unsigned int*)ga,
                    (__attribute__((address_space(3))) unsigned int*)(dst + t * 256),
                    16, 0, 0);
            }
        }
    };

    float loss_lane = 0.f;

    // ---- prologue: fill buffer 0 for iter 0 ----
    issue(wbase, my_idx[0]);

    #pragma unroll
    for (int i = 0; i < ITERS; ++i) {
        // issue next iter's DMAs into the other buffer, then wait ONLY for
        // the current buffer's 3 (older, in-order) DMAs.
        if (i + 1 < ITERS) {
            issue(wbase + ((i + 1) & 1) * BUF_W, my_idx[i + 1]);
            asm volatile("s_waitcnt vmcnt(3)" ::: "memory");
        } else {
            asm volatile("s_waitcnt vmcnt(0)" ::: "memory");
        }

        const unsigned int* buf = wbase + (i & 1) * BUF_W;
        const char* smp = (const char*)buf + sub * (21 * 64);

        // ---- ctx partial: team (g&1) sums rows team*5 .. team*5+4 ----
        vf2 cv[4] = {vf2{0.f, 0.f}, vf2{0.f, 0.f}, vf2{0.f, 0.f}, vf2{0.f, 0.f}};
        #pragma unroll
        for (int s = 0; s < 5; ++s) {
            const int r = (g & 1) * 5 + s;
            const unsigned long long w =
                *(const unsigned long long*)(smp + r * 64 + j * 8);
            vf2 f[4];
            fp8x8_to_vf2x4(w, f);
            #pragma unroll
            for (int d = 0; d < 4; ++d) cv[d] += f[d];   // v_pk_add_f32
        }
        // cross-team combine: g <-> g^1 via DPP row_ror:8 (VALU)
        #pragma unroll
        for (int d = 0; d < 4; ++d) {
            cv[d][0] = dpp_add<0x128>(cv[d][0]);
            cv[d][1] = dpp_add<0x128>(cv[d][1]);
        }
        // (1/CTX) folded into the score below

        // ---- scores: 4 rows per pass (group g -> slot 10+4p+g) ----
        #pragma unroll
        for (int p = 0; p < 3; ++p) {
            int r = 10 + 4 * p + g;                    // 10..21
            r = (r > 20) ? 20 : r;                     // g3,p2: dup (masked)
            const unsigned long long w =
                *(const unsigned long long*)(smp + r * 64 + j * 8);
            vf2 f[4];
            fp8x8_to_vf2x4(w, f);
            vf2 acc2 = {0.f, 0.f};
            #pragma unroll
            for (int d = 0; d < 4; ++d) acc2 += cv[d] * f[d];  // v_pk_fma_f32
            float prod = acc2[0] + acc2[1];
            // 8-lane reduce, all DPP: xor1, xor2, then quad-pair partner
            prod = dpp_add<0xB1>(prod);
            prod = dpp_add<0x4E>(prod);
            prod = dpp_add<0x141>(prod);

            const bool valid = (j == 0) && !(p == 2 && g == 3);
            const float sc   = prod * (1.f / CTX);
            const float z    = (p == 0 && g == 0) ? sc : -sc;
            // log(sigmoid(z)+eps) ~= -log(1+exp(-z))  (|err| <= 9e-4)
            const float c    = -__logf(1.f + __expf(-z));
            loss_lane += valid ? c : 0.f;
        }
    }

    // ---- final cross-lane reduce ----
    loss_lane += __shfl_xor(loss_lane, 1);
    loss_lane += __shfl_xor(loss_lane, 2);
    loss_lane += __shfl_xor(loss_lane, 4);
    loss_lane += __shfl_xor(loss_lane, 8);
    loss_lane += __shfl_xor(loss_lane, 16);
    loss_lane += __shfl_xor(loss_lane, 32);

    __shared__ float s_part[TPB / 64];
    if (lane == 0) s_part[wave] = loss_lane;
    __syncthreads();
    if (threadIdx.x == 0) {
        float s = 0.f;
        #pragma unroll
        for (int w = 0; w < TPB / 64; ++w) s += s_part[w];
        partials[blockIdx.x] = s;
    }
}

// ---- fallback (f32 tables) if ws_size is too small ----
__global__ __launch_bounds__(TPB) void cbow_loss_f32(
    const int*   __restrict__ ctx_idx, const int* __restrict__ pos_idx,
    const int*   __restrict__ neg_idx, const float* __restrict__ inW,
    const float* __restrict__ outW,    float* __restrict__ partials)
{
    const int lane = threadIdx.x & 63;
    const int sub  = lane >> 5;
    const int l    = lane & 31;
    const int p    = (l < 25) ? l : 24;
    const bool act = (l < 25);
    const int wave   = threadIdx.x >> 6;
    const int gwave  = blockIdx.x * (TPB / 64) + wave;
    const float2* inW2  = (const float2*)inW;
    const float2* outW2 = (const float2*)outW;

    float loss_lane = 0.f;
    for (int pair = gwave; pair < PAIRS; pair += NWAVES) {
        const int b = 2 * pair + sub;
        float cvx = 0.f, cvy = 0.f;
        #pragma unroll
        for (int jj = 0; jj < CTX; ++jj) {
            const float2 v = inW2[ctx_idx[b * CTX + jj] * 25 + p];
            cvx += v.x; cvy += v.y;
        }
        cvx *= (1.f / CTX); cvy *= (1.f / CTX);
        float packed = 0.f;
        #pragma unroll
        for (int r = 0; r <= NEG; ++r) {
            const int idx = (r == 0) ? pos_idx[b] : neg_idx[b * NEG + r - 1];
            const float2 v = outW2[idx * 25 + p];
            float prod = act ? (cvx * v.x + cvy * v.y) : 0.f;
            prod += __shfl_xor(prod, 1);
            prod += __shfl_xor(prod, 2);
            prod += __shfl_xor(prod, 4);
            prod += __shfl_xor(prod, 8);
            prod += __shfl_xor(prod, 16);
            packed = (l == r) ? prod : packed;
        }
        const float z   = (l == 0) ? packed : -packed;
        const float sig = 1.f / (1.f + __expf(-z));
        loss_lane += (l < NEG + 1) ? __logf(sig + EPS_F) : 0.f;
    }
    loss_lane += __shfl_xor(loss_lane, 1);
    loss_lane += __shfl_xor(loss_lane, 2);
    loss_lane += __shfl_xor(loss_lane, 4);
    loss_lane += __shfl_xor(loss_lane, 8);
    loss_lane += __shfl_xor(loss_lane, 16);
    loss_lane += __shfl_xor(loss_lane, 32);
    __shared__ float s_part[TPB / 64];
    if (lane == 0) s_part[wave] = loss_lane;
    __syncthreads();
    if (threadIdx.x == 0) {
        float s = 0.f;
        #pragma unroll
        for (int w = 0; w < TPB / 64; ++w) s += s_part[w];
        partials[blockIdx.x] = s;
    }
}

__global__ __launch_bounds__(256) void cbow_finalize(
    const float* __restrict__ partials, float* __restrict__ out)
{
    float s = 0.f;
    for (int i = threadIdx.x; i < BLOCKS; i += 256) s += partials[i];
    #pragma unroll
    for (int k = 32; k >= 1; k >>= 1) s += __shfl_xor(s, k);
    __shared__ float sm[4];
    const int w = threadIdx.x >> 6;
    if ((threadIdx.x & 63) == 0) sm[w] = s;
    __syncthreads();
    if (threadIdx.x == 0)
        out[0] = -(sm[0] + sm[1] + sm[2] + sm[3]) * (1.f / (float)B_TOT);
}

extern "C" void kernel_launch(void* const* d_in, const int* in_sizes, int n_in,
                              void* d_out, int out_size, void* d_ws, size_t ws_size,
                              hipStream_t stream) {
    const int*   ctx_idx = (const int*)  d_in[0];
    const int*   pos_idx = (const int*)  d_in[1];
    const int*   neg_idx = (const int*)  d_in[2];
    const float* inW     = (const float*)d_in[3];
    const float* outW    = (const float*)d_in[4];
    float*       out     = (float*)d_out;

    if (ws_size >= WS_NEED) {
        unsigned int* ws8w = (unsigned int*)d_ws;
        float* partials = (float*)((char*)d_ws + 2 * TAB8_B);
        const int conv_threads = 2 * VOCAB * 16;
        cbow_convert<<<(conv_threads + 255) / 256, 256, 0, stream>>>(inW, outW, ws8w);
        cbow_loss_fp8<<<BLOCKS, TPB, 0, stream>>>(
            ctx_idx, pos_idx, neg_idx, (const unsigned short*)d_ws, partials);
        cbow_finalize<<<1, 256, 0, stream>>>(partials, out);
    } else {
        float* partials = (float*)d_ws;
        cbow_loss_f32<<<BLOCKS, TPB, 0, stream>>>(ctx_idx, pos_idx, neg_idx, inW, outW, partials);
        cbow_finalize<<<1, 256, 0, stream>>>(partials, out);
    }
}

// Round 6
// 110.003 us; speedup vs baseline: 2.1803x; 1.0101x over previous
//
#include <hip/hip_runtime.h>
#include <hip/hip_fp8.h>

// Problem constants (from reference)
#define VOCAB 50000
#define DIM   50
#define B_TOT 131072
#define CTX   10
#define NEG   10
#define EPS_F 1e-10f
#define PAIRS (B_TOT / 2)

constexpr int TPB    = 256;   // 4 waves
constexpr int BLOCKS = 4096;  // 16384 waves x 4 pair-iterations (exact)
constexpr int NWAVES = BLOCKS * (TPB / 64);
constexpr int ITERS  = PAIRS / NWAVES;           // = 4
static_assert(PAIRS % NWAVES == 0, "exact division required");

// fp8 table layout in d_ws: each row padded to ONE aligned 64B line.
constexpr size_t ROW8_B  = 64;
constexpr size_t TAB8_B  = (size_t)VOCAB * ROW8_B;   // 3.2 MB per table
constexpr size_t WS_NEED = 2 * TAB8_B + BLOCKS * 4;

// R18 vs R17 (111.1us; loss ~36.5 vs ~34 "fetch floor"): falsify the floor's
// mechanism. 2.75M random 64B gathers is only ~5us of L2/TCP *bandwidth*, yet
// fetch-only measured ~34us -> suspect a shallow per-CU outstanding-request
// queue on the global_load_lds (LDS-DMA) path: rate = outstanding/latency
// (~0.13 lines/cyc/CU ~= 5 DMA instrs in flight @ ~600cy L2/LLC latency).
// Fix under test (T14 reg-staging): gather each row-fragment with regular
// global_load_dwordx4 into VGPRs (deep per-wave vmcnt queue; 28 waves x 3
// instrs per CU in flight), compute the current LDS buffer while loads fly,
// then ds_write_b128 into the other buffer. Addressing/layout/arithmetic
// bit-identical; shfl stays before any lane masking (R10 rule). All manual
// s_waitcnt asm removed - compiler tracks vmcnt (st reads) and lgkmcnt
// (ds_write -> ds_read) itself.
// If neutral: both paths share the same TCP limit -> gather floor confirmed
// structurally; declare roofline.
// Retained: fp8 64B-line rows (R7), stride-21 LDS + team-split ctx + all-DPP
// reductions (R10/R11), float2 packed math + -log1pexp loss (R12), preloaded
// indices + double-buffered LDS (R13), dword-store convert (R16).
constexpr int BUF_W = 42 * 16;       // 672 words = 2688 B per wave buffer

typedef float vf2 __attribute__((ext_vector_type(2)));
typedef unsigned int vu4 __attribute__((ext_vector_type(4)));

static __device__ __forceinline__ void fp8x8_to_vf2x4(unsigned long long w,
                                                      vf2* f) {
#if __has_builtin(__builtin_amdgcn_cvt_pk_f32_fp8)
    const int lo = (int)(unsigned int)w;
    const int hi = (int)(unsigned int)(w >> 32);
    f[0] = __builtin_amdgcn_cvt_pk_f32_fp8(lo, false);
    f[1] = __builtin_amdgcn_cvt_pk_f32_fp8(lo, true);
    f[2] = __builtin_amdgcn_cvt_pk_f32_fp8(hi, false);
    f[3] = __builtin_amdgcn_cvt_pk_f32_fp8(hi, true);
#else
    #pragma unroll
    for (int i = 0; i < 4; ++i) {
        __hip_fp8_e4m3 a, b;
        a.__x = (unsigned char)(w >> (16 * i));
        b.__x = (unsigned char)(w >> (16 * i + 8));
        f[i][0] = (float)a;
        f[i][1] = (float)b;
    }
#endif
}

static __device__ __forceinline__ int fp8pk(float x, float y) {
#if __has_builtin(__builtin_amdgcn_cvt_pk_fp8_f32)
    return __builtin_amdgcn_cvt_pk_fp8_f32(x, y, 0, false) & 0xffff;
#else
    __hip_fp8_e4m3 a(x), b(y);
    return (int)(a.__x | (b.__x << 8));
#endif
}

// x + partner(x) via DPP (VALU pipe). CTRL: 0xB1 quad xor1, 0x4E quad xor2,
// 0x141 row_half_mirror (quad-pair partner once quads are uniform),
// 0x128 row_ror:8 (pairs 8-lane groups within 16-lane rows).
template <int CTRL>
static __device__ __forceinline__ float dpp_add(float x) {
    const int y = __builtin_amdgcn_mov_dpp(__float_as_int(x), CTRL, 0xF, 0xF, true);
    return x + __int_as_float(y);
}

// ---- prologue: f32 tables -> fp8 rows padded to 64B lines ----
// Dword stores: 2 fp8-pairs per thread; byte layout verified on HW (R16/R17).
__global__ __launch_bounds__(256) void cbow_convert(
    const float* __restrict__ inW, const float* __restrict__ outW,
    unsigned int* __restrict__ ws8w)    // 2*VOCAB*16 dwords (64B rows)
{
    const int t = blockIdx.x * 256 + threadIdx.x;
    const int per_tab = VOCAB * 16;
    if (t >= 2 * per_tab) return;
    const int tab = t / per_tab;
    const int rem = t - tab * per_tab;
    const int r   = rem >> 4;
    const int j2  = rem & 15;            // dword within the 64B row

    unsigned int u = 0;
    if (j2 < 13) {                       // dwords 0..12 carry 50 values
        const float2* src2 = (const float2*)(tab ? outW : inW);
        const float2 v0 = src2[r * 25 + 2 * j2];
        int pk = fp8pk(v0.x, v0.y);
        if (j2 < 12) {
            const float2 v1 = src2[r * 25 + 2 * j2 + 1];
            pk |= fp8pk(v1.x, v1.y) << 16;
        }
        u = (unsigned int)pk;
    }
    ws8w[(size_t)tab * per_tab + (size_t)r * 16 + j2] = u;
}

// ---- main (R13 core, reg-staged gather instead of global_load_lds) ----
__global__ __launch_bounds__(TPB, 7) void cbow_loss_fp8(
    const int* __restrict__ ctx_idx,    // [B, CTX]
    const int* __restrict__ pos_idx,    // [B]
    const int* __restrict__ neg_idx,    // [B, NEG]
    const unsigned short* __restrict__ ws8,  // fp8 tables (in | out)
    float* __restrict__ partials)       // [BLOCKS]
{
    // double-buffered: 2 x 42 rows x 64B per wave
    __shared__ unsigned int lds[(TPB / 64) * 2 * BUF_W];   // 21504 B

    const int lane = threadIdx.x & 63;
    const int sub  = lane >> 5;          // half-wave -> sample
    const int l    = lane & 31;
    const int quad = lane >> 2;          // 0..15: row within a 16-row group
    const int qb   = (lane & 3) * 16;    // byte offset within the 64B row
    const int g    = (l >> 3) & 3;       // 8-lane group within half-wave
    const int j    = l & 7;              // lane within group

    const int wave  = threadIdx.x >> 6;
    unsigned int* wbase = lds + wave * (2 * BUF_W);
    const int gwave = blockIdx.x * (TPB / 64) + wave;

    const char* in8  = (const char*)ws8;
    const char* out8 = (const char*)(ws8 + (size_t)VOCAB * 32);

    // lane -> index slot: l<10: ctx[l]; l==10: pos; 11..20: neg[l-11]
    auto idx_addr = [&](int b) -> const int* {
        if (l < CTX)           return ctx_idx + b * CTX + l;
        if (l == CTX)          return pos_idx + b;
        if (l < CTX + 1 + NEG) return neg_idx + b * NEG + (l - CTX - 1);
        return pos_idx + b;    // lanes 21..31: harmless dummy
    };

    // ---- preload ALL iteration indices (compiler tracks the vmcnt) ----
    int my_idx[ITERS];
    #pragma unroll
    for (int i = 0; i < ITERS; ++i)
        my_idx[i] = *idx_addr(2 * (gwave + i * NWAVES) + sub);

    // 42 rows (2 samples x 21, stride 21 rows): lane's 16B fragment of row
    // (t*16+quad).  Regular VMEM loads -> deep per-wave outstanding queue.
    // shfl is computed with ALL lanes active; only the load is predicated.
    auto gather = [&](vu4* st, int midx) {
        #pragma unroll
        for (int t = 0; t < 3; ++t) {
            const int row  = t * 16 + quad;            // 0..47
            const int crow = (row > 41) ? 41 : row;    // clamp dead rows
            const int sample = (crow >= 21) ? 1 : 0;
            const int slot   = crow - 21 * sample;     // 0..20
            const int idx = __shfl(midx, sample * 32 + slot);
            const char* tb = (slot < CTX) ? in8 : out8;
            const char* ga = tb + ((size_t)(unsigned)idx << 6) + qb;
            if (t < 2 || lane < 40)                    // rows 42..47: none
                st[t] = *(const vu4*)ga;
        }
    };
    // same destination layout as the old LDS-DMA: wave-uniform base + lane*16B
    auto write_lds = [&](unsigned int* dst, const vu4* st) {
        #pragma unroll
        for (int t = 0; t < 3; ++t)
            if (t < 2 || lane < 40)
                *(vu4*)(dst + t * 256 + lane * 4) = st[t];
    };

    float loss_lane = 0.f;
    vu4 st[3];

    // ---- prologue: stage iter 0 into buffer 0 ----
    gather(st, my_idx[0]);
    write_lds(wbase, st);

    #pragma unroll
    for (int i = 0; i < ITERS; ++i) {
        // T14 issue-early: launch next iter's gathers before computing;
        // their latency hides under this iter's compute.
        if (i + 1 < ITERS) gather(st, my_idx[i + 1]);

        const unsigned int* buf = wbase + (i & 1) * BUF_W;
        const char* smp = (const char*)buf + sub * (21 * 64);

        // ---- ctx partial: team (g&1) sums rows team*5 .. team*5+4 ----
        vf2 cv[4] = {vf2{0.f, 0.f}, vf2{0.f, 0.f}, vf2{0.f, 0.f}, vf2{0.f, 0.f}};
        #pragma unroll
        for (int s = 0; s < 5; ++s) {
            const int r = (g & 1) * 5 + s;
            const unsigned long long w =
                *(const unsigned long long*)(smp + r * 64 + j * 8);
            vf2 f[4];
            fp8x8_to_vf2x4(w, f);
            #pragma unroll
            for (int d = 0; d < 4; ++d) cv[d] += f[d];   // v_pk_add_f32
        }
        // cross-team combine: g <-> g^1 via DPP row_ror:8 (VALU)
        #pragma unroll
        for (int d = 0; d < 4; ++d) {
            cv[d][0] = dpp_add<0x128>(cv[d][0]);
            cv[d][1] = dpp_add<0x128>(cv[d][1]);
        }
        // (1/CTX) folded into the score below

        // ---- scores: 4 rows per pass (group g -> slot 10+4p+g) ----
        #pragma unroll
        for (int p = 0; p < 3; ++p) {
            int r = 10 + 4 * p + g;                    // 10..21
            r = (r > 20) ? 20 : r;                     // g3,p2: dup (masked)
            const unsigned long long w =
                *(const unsigned long long*)(smp + r * 64 + j * 8);
            vf2 f[4];
            fp8x8_to_vf2x4(w, f);
            vf2 acc2 = {0.f, 0.f};
            #pragma unroll
            for (int d = 0; d < 4; ++d) acc2 += cv[d] * f[d];  // v_pk_fma_f32
            float prod = acc2[0] + acc2[1];
            // 8-lane reduce, all DPP: xor1, xor2, then quad-pair partner
            prod = dpp_add<0xB1>(prod);
            prod = dpp_add<0x4E>(prod);
            prod = dpp_add<0x141>(prod);

            const bool valid = (j == 0) && !(p == 2 && g == 3);
            const float sc   = prod * (1.f / CTX);
            const float z    = (p == 0 && g == 0) ? sc : -sc;
            // log(sigmoid(z)+eps) ~= -log(1+exp(-z))  (|err| <= 9e-4)
            const float c    = -__logf(1.f + __expf(-z));
            loss_lane += valid ? c : 0.f;
        }

        // T14 write-late: stage the (already-arrived) next tile into the
        // other buffer; per-wave private buffers -> no barrier needed.
        if (i + 1 < ITERS) write_lds(wbase + ((i + 1) & 1) * BUF_W, st);
    }

    // ---- final cross-lane reduce ----
    loss_lane += __shfl_xor(loss_lane, 1);
    loss_lane += __shfl_xor(loss_lane, 2);
    loss_lane += __shfl_xor(loss_lane, 4);
    loss_lane += __shfl_xor(loss_lane, 8);
    loss_lane += __shfl_xor(loss_lane, 16);
    loss_lane += __shfl_xor(loss_lane, 32);

    __shared__ float s_part[TPB / 64];
    if (lane == 0) s_part[wave] = loss_lane;
    __syncthreads();
    if (threadIdx.x == 0) {
        float s = 0.f;
        #pragma unroll
        for (int w = 0; w < TPB / 64; ++w) s += s_part[w];
        partials[blockIdx.x] = s;
    }
}

// ---- fallback (f32 tables) if ws_size is too small ----
__global__ __launch_bounds__(TPB) void cbow_loss_f32(
    const int*   __restrict__ ctx_idx, const int* __restrict__ pos_idx,
    const int*   __restrict__ neg_idx, const float* __restrict__ inW,
    const float* __restrict__ outW,    float* __restrict__ partials)
{
    const int lane = threadIdx.x & 63;
    const int sub  = lane >> 5;
    const int l    = lane & 31;
    const int p    = (l < 25) ? l : 24;
    const bool act = (l < 25);
    const int wave   = threadIdx.x >> 6;
    const int gwave  = blockIdx.x * (TPB / 64) + wave;
    const float2* inW2  = (const float2*)inW;
    const float2* outW2 = (const float2*)outW;

    float loss_lane = 0.f;
    for (int pair = gwave; pair < PAIRS; pair += NWAVES) {
        const int b = 2 * pair + sub;
        float cvx = 0.f, cvy = 0.f;
        #pragma unroll
        for (int jj = 0; jj < CTX; ++jj) {
            const float2 v = inW2[ctx_idx[b * CTX + jj] * 25 + p];
            cvx += v.x; cvy += v.y;
        }
        cvx *= (1.f / CTX); cvy *= (1.f / CTX);
        float packed = 0.f;
        #pragma unroll
        for (int r = 0; r <= NEG; ++r) {
            const int idx = (r == 0) ? pos_idx[b] : neg_idx[b * NEG + r - 1];
            const float2 v = outW2[idx * 25 + p];
            float prod = act ? (cvx * v.x + cvy * v.y) : 0.f;
            prod += __shfl_xor(prod, 1);
            prod += __shfl_xor(prod, 2);
            prod += __shfl_xor(prod, 4);
            prod += __shfl_xor(prod, 8);
            prod += __shfl_xor(prod, 16);
            packed = (l == r) ? prod : packed;
        }
        const float z   = (l == 0) ? packed : -packed;
        const float sig = 1.f / (1.f + __expf(-z));
        loss_lane += (l < NEG + 1) ? __logf(sig + EPS_F) : 0.f;
    }
    loss_lane += __shfl_xor(loss_lane, 1);
    loss_lane += __shfl_xor(loss_lane, 2);
    loss_lane += __shfl_xor(loss_lane, 4);
    loss_lane += __shfl_xor(loss_lane, 8);
    loss_lane += __shfl_xor(loss_lane, 16);
    loss_lane += __shfl_xor(loss_lane, 32);
    __shared__ float s_part[TPB / 64];
    if (lane == 0) s_part[wave] = loss_lane;
    __syncthreads();
    if (threadIdx.x == 0) {
        float s = 0.f;
        #pragma unroll
        for (int w = 0; w < TPB / 64; ++w) s += s_part[w];
        partials[blockIdx.x] = s;
    }
}

__global__ __launch_bounds__(256) void cbow_finalize(
    const float* __restrict__ partials, float* __restrict__ out)
{
    float s = 0.f;
    for (int i = threadIdx.x; i < BLOCKS; i += 256) s += partials[i];
    #pragma unroll
    for (int k = 32; k >= 1; k >>= 1) s += __shfl_xor(s, k);
    __shared__ float sm[4];
    const int w = threadIdx.x >> 6;
    if ((threadIdx.x & 63) == 0) sm[w] = s;
    __syncthreads();
    if (threadIdx.x == 0)
        out[0] = -(sm[0] + sm[1] + sm[2] + sm[3]) * (1.f / (float)B_TOT);
}

extern "C" void kernel_launch(void* const* d_in, const int* in_sizes, int n_in,
                              void* d_out, int out_size, void* d_ws, size_t ws_size,
                              hipStream_t stream) {
    const int*   ctx_idx = (const int*)  d_in[0];
    const int*   pos_idx = (const int*)  d_in[1];
    const int*   neg_idx = (const int*)  d_in[2];
    const float* inW     = (const float*)d_in[3];
    const float* outW    = (const float*)d_in[4];
    float*       out     = (float*)d_out;

    if (ws_size >= WS_NEED) {
        unsigned int* ws8w = (unsigned int*)d_ws;
        float* partials = (float*)((char*)d_ws + 2 * TAB8_B);
        const int conv_threads = 2 * VOCAB * 16;
        cbow_convert<<<(conv_threads + 255) / 256, 256, 0, stream>>>(inW, outW, ws8w);
        cbow_loss_fp8<<<BLOCKS, TPB, 0, stream>>>(
            ctx_idx, pos_idx, neg_idx, (const unsigned short*)d_ws, partials);
        cbow_finalize<<<1, 256, 0, stream>>>(partials, out);
    } else {
        float* partials = (float*)d_ws;
        cbow_loss_f32<<<BLOCKS, TPB, 0, stream>>>(ctx_idx, pos_idx, neg_idx, inW, outW, partials);
        cbow_finalize<<<1, 256, 0, stream>>>(partials, out);
    }
}